// Round 1
// baseline (476.585 us; speedup 1.0000x reference)
//
#include <hip/hip_runtime.h>
#include <math.h>

// ============================================================================
// GetImportantStruct: graph pooling/edge-drop op.
// Pipeline (all device-side, no host sync; sizes of outputs 1,2,4,5,6 are
// data-dependent -> computed via device prefix sums, offsets derived from
// device scalars totals[0..2] = {e_kept, n_kept, kc}).
// Whole d_out treated as float32; integer outputs written as (float)v.
// ============================================================================

// ---------------- counting ----------------
__global__ void k_count(const int* __restrict__ b, int n, int* __restrict__ cnt){
  int i = blockIdx.x*blockDim.x + threadIdx.x;
  if (i < n) atomicAdd(&cnt[b[i]], 1);
}

// ---------------- G-length exclusive scans (single block, 512 threads) ------
__device__ void scan512_excl(const int* __restrict__ in, int* __restrict__ out,
                             int G, int* s){
  int t = threadIdx.x;
  int v = (t < G) ? in[t] : 0;
  s[t] = v; __syncthreads();
  for (int off = 1; off < 512; off <<= 1){
    int add = (t >= off) ? s[t - off] : 0;
    __syncthreads();
    s[t] += add;
    __syncthreads();
  }
  if (t < G) out[t] = s[t] - v;
  __syncthreads();
}

__global__ void k_scanG(const int* __restrict__ counts, const int* __restrict__ counts2,
                        const int* __restrict__ edge_num, int G,
                        int* __restrict__ node_off, int* __restrict__ node_off2,
                        int* __restrict__ e_off){
  __shared__ int s[512];
  scan512_excl(counts,  node_off,  G, s);
  scan512_excl(counts2, node_off2, G, s);
  scan512_excl(edge_num, e_off,    G, s);
}

// ---------------- score / x_out / low / rem-init (block per node) -----------
__global__ void __launch_bounds__(128) k_score(
    const float* __restrict__ x, const float* __restrict__ W,
    const int* __restrict__ batch, const int* __restrict__ counts,
    const int* __restrict__ node_off,
    float* __restrict__ out_x, int* __restrict__ low, int* __restrict__ rem,
    int C){
  int i = blockIdx.x;
  int t = threadIdx.x;
  const float4* x4 = (const float4*)(x + (size_t)i * C);
  const float4* W4 = (const float4*)W;
  int nv = C >> 2;
  float acc = 0.f;
  for (int k = t; k < nv; k += 128){
    float4 a = x4[k]; float4 w = W4[k];
    acc += a.x*w.x + a.y*w.y + a.z*w.z + a.w*w.w;
  }
  __shared__ float lds[128];
  __shared__ float s_scale;
  lds[t] = acc; __syncthreads();
  for (int off = 64; off > 0; off >>= 1){
    if (t < off) lds[t] += lds[t + off];
    __syncthreads();
  }
  if (t == 0){
    float m  = lds[0] / (float)C;
    float sc = 1.0f / (1.0f + expf(-m));
    int g    = batch[i];
    int last = node_off[g] + counts[g] - 1;
    low[i]   = (sc < 0.5f) && (i != last) ? 1 : 0;
    rem[i]   = -1;
    s_scale  = 2.0f * sc;   // *2 is exact, so x*(2s) == (x*s)*2
  }
  __syncthreads();
  float sc2 = s_scale;
  float4* o4 = (float4*)(out_x + (size_t)i * C);
  for (int k = t; k < nv; k += 128){
    float4 a = x4[k];
    a.x *= sc2; a.y *= sc2; a.z *= sc2; a.w *= sc2;
    o4[k] = a;
  }
}

// ---------------- edge graph lookup -----------------------------------------
__device__ __forceinline__ int find_graph(const int* __restrict__ e_off, int G, int e){
  int lo = 0, hi = G - 1;            // largest g with e_off[g] <= e
  while (lo < hi){
    int mid = (lo + hi + 1) >> 1;
    if (e_off[mid] <= e) lo = mid; else hi = mid - 1;
  }
  return lo;
}

// ---------------- candidate edges: rem[src] = max candidate edge ------------
__global__ void k_cand(const int* __restrict__ ei, const int* __restrict__ e_off,
                       const int* __restrict__ node_off, const int* __restrict__ counts,
                       const int* __restrict__ batch, const int* __restrict__ low,
                       int* __restrict__ rem, int E, int G){
  int e = blockIdx.x*blockDim.x + threadIdx.x;
  if (e >= E) return;
  int g  = find_graph(e_off, G, e);
  int lp = e - e_off[g];
  if (lp < 1) return;
  int dst  = ei[E + e];
  int last = node_off[g] + counts[g] - 1;
  if (dst != last) return;
  int src = ei[e];
  if (!low[src]) return;
  if (batch[src] != g) return;
  atomicMax(&rem[src], e);
}

// dropped-edge count per graph (edge dropped iff rem[src]==e)
__global__ void k_dropcnt(const int* __restrict__ ei, const int* __restrict__ rem,
                          const int* __restrict__ e_off, int* __restrict__ dropcnt,
                          int E, int G){
  int e = blockIdx.x*blockDim.x + threadIdx.x;
  if (e >= E) return;
  if (rem[ei[e]] == e){
    int g = find_graph(e_off, G, e);
    atomicAdd(&dropcnt[g], 1);
  }
}

// ---------------- generic scan pieces ---------------------------------------
__device__ __forceinline__ int excl_scan256(int v, int* s){
  int t = threadIdx.x;
  s[t] = v; __syncthreads();
  for (int off = 1; off < 256; off <<= 1){
    int add = (t >= off) ? s[t - off] : 0;
    __syncthreads();
    s[t] += add;
    __syncthreads();
  }
  return s[t] - v;
}

__global__ void k_blocksum_edge(const int* __restrict__ ei, const int* __restrict__ rem,
                                int E, int* __restrict__ bsums){
  int t = threadIdx.x;
  int e = blockIdx.x*256 + t;
  int v = 0;
  if (e < E) v = (rem[ei[e]] != e) ? 1 : 0;
  __shared__ int s[256];
  s[t] = v; __syncthreads();
  for (int off = 128; off > 0; off >>= 1){
    if (t < off) s[t] += s[t + off];
    __syncthreads();
  }
  if (t == 0) bsums[blockIdx.x] = s[0];
}

__global__ void k_blocksum_mask(const int* __restrict__ mask, int n, int* __restrict__ bsums){
  int t = threadIdx.x;
  int e = blockIdx.x*256 + t;
  int v = (e < n) ? mask[e] : 0;
  __shared__ int s[256];
  s[t] = v; __syncthreads();
  for (int off = 128; off > 0; off >>= 1){
    if (t < off) s[t] += s[t + off];
    __syncthreads();
  }
  if (t == 0) bsums[blockIdx.x] = s[0];
}

__global__ void k_blocksum_bredge(const int* __restrict__ bi, const int* __restrict__ remap,
                                  int EB, int* __restrict__ bsums){
  int t = threadIdx.x;
  int e = blockIdx.x*256 + t;
  int v = 0;
  if (e < EB) v = (remap[bi[e]] >= 0 && remap[bi[EB + e]] >= 0) ? 1 : 0;
  __shared__ int s[256];
  s[t] = v; __syncthreads();
  for (int off = 128; off > 0; off >>= 1){
    if (t < off) s[t] += s[t + off];
    __syncthreads();
  }
  if (t == 0) bsums[blockIdx.x] = s[0];
}

// single-block scan of up to 1024 block sums; emits total
__global__ void k_scan_bsums(int* __restrict__ bsums, int nb, int* __restrict__ total){
  __shared__ int s[1024];
  int t = threadIdx.x;
  int v = (t < nb) ? bsums[t] : 0;
  s[t] = v; __syncthreads();
  for (int off = 1; off < 1024; off <<= 1){
    int add = (t >= off) ? s[t - off] : 0;
    __syncthreads();
    s[t] += add;
    __syncthreads();
  }
  if (t < nb)     bsums[t] = s[t] - v;
  if (t == nb-1)  *total   = s[t];
}

// ---------------- edge compaction write -------------------------------------
__global__ void k_edge_scanwrite(const int* __restrict__ ei, const int* __restrict__ rem,
                                 const int* __restrict__ bsums, const int* __restrict__ totals,
                                 int* __restrict__ edge_pos, float* __restrict__ out,
                                 long long base0, int E){
  __shared__ int s[256];
  int t = threadIdx.x;
  int e = blockIdx.x*256 + t;
  int keep = 0, src = 0, dst = 0;
  if (e < E){ src = ei[e]; dst = ei[E + e]; keep = (rem[src] != e) ? 1 : 0; }
  int excl = excl_scan256(keep, s);
  if (e < E){
    if (keep){
      int p = bsums[blockIdx.x] + excl;
      edge_pos[e] = p;
      long long ek = totals[0];
      out[base0 + p]      = (float)src;
      out[base0 + ek + p] = (float)dst;
    } else {
      edge_pos[e] = -1;
    }
  }
}

__global__ void k_edgenum_out(const int* __restrict__ edge_num, const int* __restrict__ dropcnt,
                              const int* __restrict__ totals, float* __restrict__ out,
                              long long base0, int DE, int G){
  int g = blockIdx.x*blockDim.x + threadIdx.x;
  if (g >= G) return;
  long long ek   = totals[0];
  long long off3 = base0 + 2*ek + ek*(long long)DE;
  out[off3 + g] = (float)(edge_num[g] - dropcnt[g]);
}

// copy kept edge_inform rows (block per edge; off2 is even -> float2 ok)
__global__ void __launch_bounds__(64) k_inform_copy(const float* __restrict__ inform,
    const int* __restrict__ edge_pos, const int* __restrict__ totals,
    float* __restrict__ out, long long base0, int DE){
  int e = blockIdx.x;
  int p = edge_pos[e];
  if (p < 0) return;
  long long ek   = totals[0];
  long long off2 = base0 + 2*ek;
  const float2* in2 = (const float2*)(inform + (size_t)e * DE);
  float2*       o2  = (float2*)(out + off2 + (long long)p * DE);
  for (int t = threadIdx.x; t < (DE >> 1); t += 64) o2[t] = in2[t];
}

// ---------------- br side ----------------------------------------------------
__global__ void k_set1(int* __restrict__ p, int n){
  int i = blockIdx.x*blockDim.x + threadIdx.x;
  if (i < n) p[i] = 1;
}

__global__ void k_brdrop(const int* __restrict__ low, const int* __restrict__ batch,
                         const int* __restrict__ node_off, const int* __restrict__ node_off2,
                         const int* __restrict__ br_com_num, int* __restrict__ brmask, int N){
  int i = blockIdx.x*blockDim.x + threadIdx.x;
  if (i >= N) return;
  if (!low[i]) return;
  int g = batch[i];
  int d = i - node_off[g] + br_com_num[g] + node_off2[g];
  brmask[d] = 0;
}

__global__ void k_node_scanwrite(const int* __restrict__ mask, const int* __restrict__ bsums,
                                 int* __restrict__ remap, int n){
  __shared__ int s[256];
  int t = threadIdx.x;
  int j = blockIdx.x*256 + t;
  int keep = (j < n) ? mask[j] : 0;
  int excl = excl_scan256(keep, s);
  if (j < n) remap[j] = keep ? (bsums[blockIdx.x] + excl) : -1;
}

__global__ void k_bredge_scanwrite(const int* __restrict__ bi, const int* __restrict__ remap,
                                   const int* __restrict__ bsums, const int* __restrict__ totals,
                                   float* __restrict__ out, long long base0,
                                   int G, int DE, int C, int EB){
  __shared__ int s[256];
  int t = threadIdx.x;
  int e = blockIdx.x*256 + t;
  int r = -1, c = -1, keep = 0;
  if (e < EB){
    r = remap[bi[e]];
    c = remap[bi[EB + e]];
    keep = (r >= 0 && c >= 0) ? 1 : 0;
  }
  int excl = excl_scan256(keep, s);
  if (keep){
    long long ek = totals[0], nk = totals[1], kc = totals[2];
    long long off5 = base0 + 2*ek + ek*(long long)DE + G + nk*(long long)C;
    int p = bsums[blockIdx.x] + excl;
    out[off5 + p]      = (float)r;
    out[off5 + kc + p] = (float)c;
  }
}

// copy kept br_feature rows + br_batch (block per node; off4 even -> float2 ok)
__global__ void __launch_bounds__(256) k_brfeat(const float* __restrict__ brf,
    const int* __restrict__ remap, const int* __restrict__ brb,
    const int* __restrict__ totals, float* __restrict__ out,
    long long base0, int G, int DE, int C){
  int j = blockIdx.x;
  int p = remap[j];
  if (p < 0) return;
  long long ek = totals[0], nk = totals[1], kc = totals[2];
  long long off4 = base0 + 2*ek + ek*(long long)DE + G;
  const float2* in2 = (const float2*)(brf + (size_t)j * C);
  float2*       o2  = (float2*)(out + off4 + (long long)p * C);
  for (int t = threadIdx.x; t < (C >> 1); t += 256) o2[t] = in2[t];
  if (threadIdx.x == 0){
    long long off6 = off4 + nk*(long long)C + 2*kc;
    out[off6 + p] = (float)brb[j];
  }
}

// ============================================================================
extern "C" void kernel_launch(void* const* d_in, const int* in_sizes, int n_in,
                              void* d_out, int out_size, void* d_ws, size_t ws_size,
                              hipStream_t stream){
  const float* x           = (const float*)d_in[0];
  const int*   edge_index  = (const int*)  d_in[1];
  const int*   edge_num    = (const int*)  d_in[2];
  const float* edge_inform = (const float*)d_in[3];
  const int*   batch       = (const int*)  d_in[4];
  const float* br_feature  = (const float*)d_in[5];
  const int*   br_index    = (const int*)  d_in[6];
  const int*   br_batch    = (const int*)  d_in[7];
  const int*   br_com_num  = (const int*)  d_in[8];
  const float* W           = (const float*)d_in[9];
  float* out = (float*)d_out;

  const int C  = in_sizes[9];          // W is (1, C)
  const int N  = in_sizes[4];          // batch
  const int G  = in_sizes[2];          // edge_num
  const int E  = in_sizes[1] / 2;      // edge_index (2, E)
  const int DE = in_sizes[3] / E;      // edge_inform (E, DE)
  const int N2 = in_sizes[7];          // br_batch
  const int EB = in_sizes[6] / 2;      // br_index (2, EB)

  // ---- workspace layout (ints) ----
  int* ws        = (int*)d_ws;
  int* counts    = ws;                 // G
  int* counts2   = counts    + G;      // G
  int* dropcnt   = counts2   + G;      // G  (zeroed together with counts)
  int* node_off  = dropcnt   + G;      // G
  int* node_off2 = node_off  + G;      // G
  int* e_off     = node_off2 + G;      // G
  int* totals    = e_off     + G;      // 8: [0]=e_kept [1]=n_kept [2]=kc
  int* low       = totals    + 8;      // N
  int* rem       = low       + N;      // N
  int* brmask    = rem       + N;      // N2
  int* remap     = brmask    + N2;     // N2
  int* edge_pos  = remap     + N2;     // E
  int* bsumsA    = edge_pos  + E;      // 1024
  int* bsumsB    = bsumsA    + 1024;   // 1024
  int* bsumsC    = bsumsB    + 1024;   // 1024

  const long long base0 = (long long)N * C;   // end of x_out chunk

  const int nbN  = (N  + 255) / 256;
  const int nbN2 = (N2 + 255) / 256;
  const int nbE  = (E  + 255) / 256;   // must be <= 1024
  const int nbB  = (EB + 255) / 256;   // must be <= 1024

  hipMemsetAsync(counts, 0, sizeof(int) * 3 * G, stream);

  k_count<<<nbN,  256, 0, stream>>>(batch,    N,  counts);
  k_count<<<nbN2, 256, 0, stream>>>(br_batch, N2, counts2);
  k_scanG<<<1, 512, 0, stream>>>(counts, counts2, edge_num, G,
                                 node_off, node_off2, e_off);

  k_score<<<N, 128, 0, stream>>>(x, W, batch, counts, node_off,
                                 out, low, rem, C);

  k_cand   <<<nbE, 256, 0, stream>>>(edge_index, e_off, node_off, counts,
                                     batch, low, rem, E, G);
  k_dropcnt<<<nbE, 256, 0, stream>>>(edge_index, rem, e_off, dropcnt, E, G);

  // edge compaction
  k_blocksum_edge<<<nbE, 256, 0, stream>>>(edge_index, rem, E, bsumsA);
  k_scan_bsums   <<<1, 1024, 0, stream>>>(bsumsA, nbE, &totals[0]);
  k_edge_scanwrite<<<nbE, 256, 0, stream>>>(edge_index, rem, bsumsA, totals,
                                            edge_pos, out, base0, E);
  k_edgenum_out<<<(G + 255) / 256, 256, 0, stream>>>(edge_num, dropcnt, totals,
                                                     out, base0, DE, G);
  k_inform_copy<<<E, 64, 0, stream>>>(edge_inform, edge_pos, totals,
                                      out, base0, DE);

  // br-node compaction
  k_set1  <<<nbN2, 256, 0, stream>>>(brmask, N2);
  k_brdrop<<<nbN,  256, 0, stream>>>(low, batch, node_off, node_off2,
                                     br_com_num, brmask, N);
  k_blocksum_mask<<<nbN2, 256, 0, stream>>>(brmask, N2, bsumsB);
  k_scan_bsums   <<<1, 1024, 0, stream>>>(bsumsB, nbN2, &totals[1]);
  k_node_scanwrite<<<nbN2, 256, 0, stream>>>(brmask, bsumsB, remap, N2);

  // br-edge compaction (needs remap; totals[2] before any kc-dependent write)
  k_blocksum_bredge<<<nbB, 256, 0, stream>>>(br_index, remap, EB, bsumsC);
  k_scan_bsums     <<<1, 1024, 0, stream>>>(bsumsC, nbB, &totals[2]);
  k_bredge_scanwrite<<<nbB, 256, 0, stream>>>(br_index, remap, bsumsC, totals,
                                              out, base0, G, DE, C, EB);

  // br_feature / br_batch (needs totals[0..2])
  k_brfeat<<<N2, 256, 0, stream>>>(br_feature, remap, br_batch, totals,
                                   out, base0, G, DE, C);
}

// Round 2
// 434.219 us; speedup vs baseline: 1.0976x; 1.0976x over previous
//
#include <hip/hip_runtime.h>
#include <math.h>

// ============================================================================
// GetImportantStruct — round 2: fused pipeline (11 dispatches, was 20),
// single-pass wave-per-node score kernel (register-resident row, shfl reduce).
// All device-side; data-dependent output offsets via device scalars
// totals[0..2] = {e_kept, n_kept, kc}. d_out treated as float32 throughout.
// ============================================================================

// ---------------- fused counting: batch (N) and br_batch (N2) ---------------
__global__ void k_count_both(const int* __restrict__ batch, int N,
                             const int* __restrict__ br_batch, int N2,
                             int* __restrict__ counts, int* __restrict__ counts2){
  int i = blockIdx.x*blockDim.x + threadIdx.x;
  if (i < N) atomicAdd(&counts[batch[i]], 1);
  else if (i < N + N2) atomicAdd(&counts2[br_batch[i - N]], 1);
}

// ---------------- G-length exclusive scans (single block, 512 threads) ------
__device__ void scan512_excl(const int* __restrict__ in, int* __restrict__ out,
                             int G, int* s){
  int t = threadIdx.x;
  int v = (t < G) ? in[t] : 0;
  s[t] = v; __syncthreads();
  for (int off = 1; off < 512; off <<= 1){
    int add = (t >= off) ? s[t - off] : 0;
    __syncthreads();
    s[t] += add;
    __syncthreads();
  }
  if (t < G) out[t] = s[t] - v;
  __syncthreads();
}

__global__ void k_scanG(const int* __restrict__ counts, const int* __restrict__ counts2,
                        const int* __restrict__ edge_num, int G,
                        int* __restrict__ node_off, int* __restrict__ node_off2,
                        int* __restrict__ e_off){
  __shared__ int s[512];
  scan512_excl(counts,  node_off,  G, s);
  scan512_excl(counts2, node_off2, G, s);
  scan512_excl(edge_num, e_off,    G, s);
}

// ---------------- score / x_out / low / rem-init: one WAVE per node ---------
// Row (C floats) held in registers (C<=2048 -> <=8 float4/lane), butterfly
// shfl reduction, single global pass. sigmoid(m)<0.5  <=>  dot<0.
__global__ void __launch_bounds__(256) k_score(
    const float* __restrict__ x, const float* __restrict__ W,
    const int* __restrict__ batch, const int* __restrict__ counts,
    const int* __restrict__ node_off,
    float* __restrict__ out_x, int* __restrict__ low, int* __restrict__ rem,
    int C, int N){
  int wave = (blockIdx.x * blockDim.x + threadIdx.x) >> 6;
  int lane = threadIdx.x & 63;
  if (wave >= N) return;
  const float4* x4 = (const float4*)(x + (size_t)wave * C);
  const float4* W4 = (const float4*)W;
  const int nv = C >> 2;
  float4 vals[8];
  float acc = 0.f;
  int m = 0;
  for (int k = lane; k < nv; k += 64){
    float4 a = x4[k]; float4 w = W4[k];
    acc += a.x*w.x + a.y*w.y + a.z*w.z + a.w*w.w;
    if (m < 8) vals[m] = a;
    m++;
  }
  #pragma unroll
  for (int d = 1; d < 64; d <<= 1) acc += __shfl_xor(acc, d, 64);
  // all lanes now hold the full dot product
  float scale = 2.0f / (1.0f + expf(-acc / (float)C));   // 2*sigmoid(mean)
  if (lane == 0){
    int g    = batch[wave];
    int last = node_off[g] + counts[g] - 1;
    low[wave] = (acc < 0.0f) && (wave != last) ? 1 : 0;
    rem[wave] = -1;
  }
  float4* o4 = (float4*)(out_x + (size_t)wave * C);
  m = 0;
  for (int k = lane; k < nv; k += 64){
    float4 a = (m < 8) ? vals[m] : x4[k];
    m++;
    a.x *= scale; a.y *= scale; a.z *= scale; a.w *= scale;
    o4[k] = a;
  }
}

// ---------------- edge -> graph lookup --------------------------------------
__device__ __forceinline__ int find_graph(const int* __restrict__ e_off, int G, int e){
  int lo = 0, hi = G - 1;            // largest g with e_off[g] <= e
  while (lo < hi){
    int mid = (lo + hi + 1) >> 1;
    if (e_off[mid] <= e) lo = mid; else hi = mid - 1;
  }
  return lo;
}

// ---------------- pass1: candidate edges (E) + br drop scatter (N) ----------
__global__ void k_pass1(const int* __restrict__ ei, const int* __restrict__ e_off,
                        const int* __restrict__ node_off, const int* __restrict__ node_off2,
                        const int* __restrict__ counts, const int* __restrict__ batch,
                        const int* __restrict__ low, const int* __restrict__ br_com_num,
                        int* __restrict__ rem, int* __restrict__ brmask,
                        int E, int N, int G){
  int e = blockIdx.x*blockDim.x + threadIdx.x;
  if (e < N && low[e]){                       // br-drop scatter for node e
    int g = batch[e];
    int d = e - node_off[g] + br_com_num[g] + node_off2[g];
    brmask[d] = 1;                            // 1 = dropped (mask pre-zeroed)
  }
  if (e >= E) return;
  int g  = find_graph(e_off, G, e);
  if (e - e_off[g] < 1) return;               // local_pos >= 1
  int dst  = ei[E + e];
  int last = node_off[g] + counts[g] - 1;
  if (dst != last) return;
  int src = ei[e];
  if (!low[src]) return;
  if (batch[src] != g) return;
  atomicMax(&rem[src], e);
}

// ---------------- pass2: edge keep blocksums + dropcnt (E) | brmask sums (N2)
__global__ void k_pass2(const int* __restrict__ ei, const int* __restrict__ rem,
                        const int* __restrict__ e_off, const int* __restrict__ brmask,
                        int* __restrict__ dropcnt,
                        int* __restrict__ bsumsA, int* __restrict__ bsumsB,
                        int E, int N2, int G, int nbE){
  __shared__ int s[256];
  int b = blockIdx.x, t = threadIdx.x;
  int v = 0;
  if (b < nbE){
    int e = b*256 + t;
    if (e < E){
      v = (rem[ei[e]] != e) ? 1 : 0;
      if (!v){ int g = find_graph(e_off, G, e); atomicAdd(&dropcnt[g], 1); }
    }
  } else {
    int j = (b - nbE)*256 + t;
    v = (j < N2) ? (brmask[j] == 0) : 0;
  }
  s[t] = v; __syncthreads();
  for (int off = 128; off > 0; off >>= 1){
    if (t < off) s[t] += s[t + off];
    __syncthreads();
  }
  if (t == 0){
    if (b < nbE) bsumsA[b] = s[0];
    else         bsumsB[b - nbE] = s[0];
  }
}

// ---------------- scan helpers ----------------------------------------------
__device__ void scan_bsums_dev(int* __restrict__ bsums, int nb, int* __restrict__ total){
  __shared__ int s[1024];
  int t = threadIdx.x;
  int v = (t < nb) ? bsums[t] : 0;
  s[t] = v; __syncthreads();
  for (int off = 1; off < 1024; off <<= 1){
    int add = (t >= off) ? s[t - off] : 0;
    __syncthreads();
    s[t] += add;
    __syncthreads();
  }
  if (t < nb)      bsums[t] = s[t] - v;
  if (t == nb - 1) *total   = s[t];
}

__global__ void k_scanAB(int* __restrict__ bsumsA, int nbA,
                         int* __restrict__ bsumsB, int nbB,
                         int* __restrict__ totals){
  if (blockIdx.x == 0) scan_bsums_dev(bsumsA, nbA, &totals[0]);
  else                 scan_bsums_dev(bsumsB, nbB, &totals[1]);
}

__global__ void k_scanC(int* __restrict__ bsumsC, int nb, int* __restrict__ totals){
  scan_bsums_dev(bsumsC, nb, &totals[2]);
}

__device__ __forceinline__ int excl_scan256(int v, int* s){
  int t = threadIdx.x;
  s[t] = v; __syncthreads();
  for (int off = 1; off < 256; off <<= 1){
    int add = (t >= off) ? s[t - off] : 0;
    __syncthreads();
    s[t] += add;
    __syncthreads();
  }
  return s[t] - v;
}

// ---------------- pass3: edge scan-write + edgenum (E) | node scan-write (N2)
__global__ void k_pass3(const int* __restrict__ ei, const int* __restrict__ rem,
                        const int* __restrict__ bsumsA, const int* __restrict__ bsumsB,
                        const int* __restrict__ totals,
                        const int* __restrict__ edge_num, const int* __restrict__ dropcnt,
                        const int* __restrict__ brmask,
                        int* __restrict__ edge_pos, int* __restrict__ remap,
                        float* __restrict__ out, long long base0,
                        int E, int N2, int G, int DE, int nbE){
  __shared__ int s[256];
  int b = blockIdx.x, t = threadIdx.x;
  if (b < nbE){
    int e = b*256 + t;
    int keep = 0, src = 0, dst = 0;
    if (e < E){ src = ei[e]; dst = ei[E + e]; keep = (rem[src] != e) ? 1 : 0; }
    int excl = excl_scan256(keep, s);
    long long ek = totals[0];
    if (e < E){
      if (keep){
        int p = bsumsA[b] + excl;
        edge_pos[e] = p;
        out[base0 + p]      = (float)src;
        out[base0 + ek + p] = (float)dst;
      } else edge_pos[e] = -1;
    }
    if (b == 0){
      long long off3 = base0 + 2*ek + ek*(long long)DE;
      for (int g = t; g < G; g += 256)
        out[off3 + g] = (float)(edge_num[g] - dropcnt[g]);
    }
  } else {
    int j = (b - nbE)*256 + t;
    int keep = (j < N2) ? (brmask[j] == 0) : 0;
    int excl = excl_scan256(keep, s);
    if (j < N2) remap[j] = keep ? (bsumsB[b - nbE] + excl) : -1;
  }
}

// ---------------- pass4: bredge blocksums (EB) | inform row copy (E rows) ---
__global__ void __launch_bounds__(256) k_pass4(
    const int* __restrict__ bi, const int* __restrict__ remap,
    const float* __restrict__ inform, const int* __restrict__ edge_pos,
    const int* __restrict__ totals,
    int* __restrict__ bsumsC, float* __restrict__ out,
    long long base0, int EB, int E, int DE, int nbB){
  int b = blockIdx.x, t = threadIdx.x;
  if (b < nbB){
    __shared__ int s[256];
    int e = b*256 + t;
    int v = 0;
    if (e < EB) v = (remap[bi[e]] >= 0 && remap[bi[EB + e]] >= 0) ? 1 : 0;
    s[t] = v; __syncthreads();
    for (int off = 128; off > 0; off >>= 1){
      if (t < off) s[t] += s[t + off];
      __syncthreads();
    }
    if (t == 0) bsumsC[b] = s[0];
  } else {
    // 4 edges per block, one wave each
    int e = (b - nbB)*4 + (t >> 6);
    if (e >= E) return;
    int p = edge_pos[e];
    if (p < 0) return;
    long long ek   = totals[0];
    long long off2 = base0 + 2*ek;
    int lane = t & 63;
    const float2* in2 = (const float2*)(inform + (size_t)e * DE);
    float2*       o2  = (float2*)(out + off2 + (long long)p * DE);
    for (int j = lane; j < (DE >> 1); j += 64) o2[j] = in2[j];
  }
}

// ---------------- pass5: bredge scan-write (EB) | br_feature/br_batch (N2) --
__global__ void __launch_bounds__(256) k_pass5(
    const int* __restrict__ bi, const int* __restrict__ remap,
    const int* __restrict__ bsumsC, const int* __restrict__ totals,
    const float* __restrict__ brf, const int* __restrict__ brb,
    float* __restrict__ out, long long base0,
    int G, int DE, int C, int EB, int N2, int nbB){
  int b = blockIdx.x, t = threadIdx.x;
  long long ek = totals[0], nk = totals[1], kc = totals[2];
  long long off4 = base0 + 2*ek + ek*(long long)DE + G;        // br_feature_p
  if (b < nbB){
    __shared__ int s[256];
    int e = b*256 + t;
    int r = -1, c = -1, keep = 0;
    if (e < EB){
      r = remap[bi[e]];
      c = remap[bi[EB + e]];
      keep = (r >= 0 && c >= 0) ? 1 : 0;
    }
    int excl = excl_scan256(keep, s);
    if (keep){
      long long off5 = off4 + nk*(long long)C;                 // br_index_p
      int p = bsumsC[b] + excl;
      out[off5 + p]      = (float)r;
      out[off5 + kc + p] = (float)c;
    }
  } else {
    int j = b - nbB;                                           // node row
    int p = remap[j];
    if (p < 0) return;
    const float2* in2 = (const float2*)(brf + (size_t)j * C);
    float2*       o2  = (float2*)(out + off4 + (long long)p * C);
    for (int k = t; k < (C >> 1); k += 256) o2[k] = in2[k];
    if (t == 0){
      long long off6 = off4 + nk*(long long)C + 2*kc;          // br_batch_p
      out[off6 + p] = (float)brb[j];
    }
  }
}

// ============================================================================
extern "C" void kernel_launch(void* const* d_in, const int* in_sizes, int n_in,
                              void* d_out, int out_size, void* d_ws, size_t ws_size,
                              hipStream_t stream){
  const float* x           = (const float*)d_in[0];
  const int*   edge_index  = (const int*)  d_in[1];
  const int*   edge_num    = (const int*)  d_in[2];
  const float* edge_inform = (const float*)d_in[3];
  const int*   batch       = (const int*)  d_in[4];
  const float* br_feature  = (const float*)d_in[5];
  const int*   br_index    = (const int*)  d_in[6];
  const int*   br_batch    = (const int*)  d_in[7];
  const int*   br_com_num  = (const int*)  d_in[8];
  const float* W           = (const float*)d_in[9];
  float* out = (float*)d_out;

  const int C  = in_sizes[9];          // W is (1, C)
  const int N  = in_sizes[4];          // batch
  const int G  = in_sizes[2];          // edge_num
  const int E  = in_sizes[1] / 2;      // edge_index (2, E)
  const int DE = in_sizes[3] / E;      // edge_inform (E, DE)
  const int N2 = in_sizes[7];          // br_batch
  const int EB = in_sizes[6] / 2;      // br_index (2, EB)

  // ---- workspace layout (ints); [counts..brmask] is the zeroed region ----
  int* ws        = (int*)d_ws;
  int* counts    = ws;                 // G   (zeroed)
  int* counts2   = counts    + G;      // G   (zeroed)
  int* dropcnt   = counts2   + G;      // G   (zeroed)
  int* brmask    = dropcnt   + G;      // N2  (zeroed; 0=keep, 1=dropped)
  int* node_off  = brmask    + N2;     // G
  int* node_off2 = node_off  + G;      // G
  int* e_off     = node_off2 + G;      // G
  int* totals    = e_off     + G;      // 8: [0]=e_kept [1]=n_kept [2]=kc
  int* low       = totals    + 8;      // N
  int* rem       = low       + N;      // N
  int* remap     = rem       + N;      // N2
  int* edge_pos  = remap     + N2;     // E
  int* bsumsA    = edge_pos  + E;      // 1024
  int* bsumsB    = bsumsA    + 1024;   // 1024
  int* bsumsC    = bsumsB    + 1024;   // 1024

  const long long base0 = (long long)N * C;   // end of x_out chunk

  const int nbN2 = (N2 + 255) / 256;
  const int nbE  = (E  + 255) / 256;   // <= 1024
  const int nbB  = (EB + 255) / 256;   // <= 1024

  hipMemsetAsync(counts, 0, sizeof(int) * (3 * (size_t)G + N2), stream);

  k_count_both<<<(N + N2 + 255) / 256, 256, 0, stream>>>(batch, N, br_batch, N2,
                                                         counts, counts2);
  k_scanG<<<1, 512, 0, stream>>>(counts, counts2, edge_num, G,
                                 node_off, node_off2, e_off);

  k_score<<<(N * 64 + 255) / 256, 256, 0, stream>>>(x, W, batch, counts, node_off,
                                                    out, low, rem, C, N);

  k_pass1<<<(max(E, N) + 255) / 256, 256, 0, stream>>>(
      edge_index, e_off, node_off, node_off2, counts, batch, low, br_com_num,
      rem, brmask, E, N, G);

  k_pass2<<<nbE + nbN2, 256, 0, stream>>>(edge_index, rem, e_off, brmask,
                                          dropcnt, bsumsA, bsumsB,
                                          E, N2, G, nbE);

  k_scanAB<<<2, 1024, 0, stream>>>(bsumsA, nbE, bsumsB, nbN2, totals);

  k_pass3<<<nbE + nbN2, 256, 0, stream>>>(edge_index, rem, bsumsA, bsumsB, totals,
                                          edge_num, dropcnt, brmask,
                                          edge_pos, remap, out, base0,
                                          E, N2, G, DE, nbE);

  k_pass4<<<nbB + (E + 3) / 4, 256, 0, stream>>>(br_index, remap,
                                                 edge_inform, edge_pos, totals,
                                                 bsumsC, out, base0,
                                                 EB, E, DE, nbB);

  k_scanC<<<1, 1024, 0, stream>>>(bsumsC, nbB, totals);

  k_pass5<<<nbB + N2, 256, 0, stream>>>(br_index, remap, bsumsC, totals,
                                        br_feature, br_batch, out, base0,
                                        G, DE, C, EB, N2, nbB);
}